// Round 6
// baseline (241.007 us; speedup 1.0000x reference)
//
#include <hip/hip_runtime.h>
#include <stdint.h>
#include <math.h>

#define TK 16384
#define DD 2048
#define RR 256
#define EE 8
#define HH 512
#define NSEG_MAX 264
#define NPAIR_MAX (NSEG_MAX * 128)

typedef __attribute__((ext_vector_type(4))) float f32x4;
typedef __attribute__((ext_vector_type(8))) short s16x8;
typedef __attribute__((ext_vector_type(8))) unsigned short u16x8;
typedef __attribute__((ext_vector_type(4))) unsigned u32x4;
typedef unsigned short ushort_t;

__device__ inline unsigned short f2bf(float f) {
  union { float f; unsigned u; } v; v.f = f;
  unsigned r = v.u + 0x7fffu + ((v.u >> 16) & 1u);
  return (unsigned short)(r >> 16);
}
__device__ inline float bf2f(ushort_t u) {
  union { unsigned u; float f; } v; v.u = ((unsigned)u) << 16; return v.f;
}

__device__ inline void gll16(const void* g, void* l) {
  __builtin_amdgcn_global_load_lds(
      (const __attribute__((address_space(1))) void*)g,
      (__attribute__((address_space(3))) void*)l, 16, 0, 0);
}

__device__ inline u16x8 pack8(f32x4 a, f32x4 b) {
  u16x8 r;
  r[0] = f2bf(a.x); r[1] = f2bf(a.y); r[2] = f2bf(a.z); r[3] = f2bf(a.w);
  r[4] = f2bf(b.x); r[5] = f2bf(b.y); r[6] = f2bf(b.z); r[7] = f2bf(b.w);
  return r;
}

// LDS XOR-swizzle: LDS[row][slot] = G[row][slot ^ (row&7)] (8-elem bf16 slots)
#define SWZ8(idx) (((idx & 7) ^ ((idx >> 3) & 7)) * 8)

// ---------------- fused prep: 4 transposes + VeffT + Uh + ctrl/pair zeroing -
// blocks: [0,512) V->Vt, [512,1024) U->Ut, [1024,2048) W1->W1t,
//         [2048,3072) W2->W2t, [3072,3080) VeffT, [3080,3144) Uh,
//         [3144,3211) zero ctrl+pair_t+pair_w (17152 dword4s = 274432 B)
__global__ __launch_bounds__(256) void k_prep(
    const float* __restrict__ V, const float* __restrict__ U,
    const float* __restrict__ W1, const float* __restrict__ W2,
    const float* __restrict__ Wr, const float* __restrict__ Wh,
    ushort_t* __restrict__ Vt, ushort_t* __restrict__ Ut,
    ushort_t* __restrict__ W1t, ushort_t* __restrict__ W2t,
    float* __restrict__ VeffT, float* __restrict__ Uh,
    u32x4* __restrict__ zbase) {
  __shared__ float sm[2112];
  int b = blockIdx.x, t = threadIdx.x;
  if (b < 3072) {
    const float* src; ushort_t* dst; int nr, nc, c0, r0;
    if (b < 512)       { src = V; dst = Vt; nr = 2048; nc = 256;
                         c0 = (b & 7) * 32; r0 = (b >> 3) * 32; }
    else if (b < 1024) { int bx = b - 512; src = U; dst = Ut; nr = 256; nc = 2048;
                         c0 = (bx & 63) * 32; r0 = (bx >> 6) * 32; }
    else if (b < 2048) { int bx = b - 1024; int s = bx >> 7; bx &= 127;
                         src = W1 + (size_t)s * 131072; dst = W1t + (size_t)s * 131072;
                         nr = 256; nc = 512; c0 = (bx & 15) * 32; r0 = (bx >> 4) * 32; }
    else               { int bx = b - 2048; int s = bx >> 7; bx &= 127;
                         src = W2 + (size_t)s * 131072; dst = W2t + (size_t)s * 131072;
                         nr = 512; nc = 256; c0 = (bx & 7) * 32; r0 = (bx >> 3) * 32; }
    int tx = t & 31, ty = t >> 5;
    #pragma unroll
    for (int i = 0; i < 32; i += 8)
      sm[(ty + i) * 33 + tx] = src[(size_t)(r0 + ty + i) * nc + c0 + tx];
    __syncthreads();
    #pragma unroll
    for (int i = 0; i < 32; i += 8)
      dst[(size_t)(c0 + ty + i) * nr + r0 + tx] = f2bf(sm[tx * 33 + ty + i]);
  } else if (b < 3080) {
    #pragma unroll
    for (int i = 0; i < 8; ++i) sm[i * 256 + t] = Wr[i * 256 + t];
    __syncthreads();
    int d = (b - 3072) * 256 + t;
    float a[8] = {0, 0, 0, 0, 0, 0, 0, 0};
    const float* vrow = V + (size_t)d * RR;
    for (int r = 0; r < RR; r += 4) {
      f32x4 v = *(const f32x4*)(vrow + r);
      #pragma unroll
      for (int e = 0; e < 8; ++e)
        a[e] += v.x * sm[r * 8 + e] + v.y * sm[(r + 1) * 8 + e] +
                v.z * sm[(r + 2) * 8 + e] + v.w * sm[(r + 3) * 8 + e];
    }
    #pragma unroll
    for (int e = 0; e < 8; ++e) VeffT[(size_t)e * DD + d] = a[e];
  } else if (b < 3144) {
    int wave = t >> 6, lane = t & 63;
    int r = (b - 3080) * 4 + wave;
    const f32x4* u4 = (const f32x4*)(U + (size_t)r * DD);
    const f32x4* w4 = (const f32x4*)Wh;
    float acc = 0.f;
    #pragma unroll
    for (int it = 0; it < 8; ++it) {
      f32x4 a = u4[it * 64 + lane], bb = w4[it * 64 + lane];
      acc += a.x * bb.x + a.y * bb.y + a.z * bb.z + a.w * bb.w;
    }
    #pragma unroll
    for (int o = 32; o; o >>= 1) acc += __shfl_down(acc, o, 64);
    if (lane == 0) Uh[r] = acc;
  } else {
    int i = (b - 3144) * 256 + t;      // 67 blocks * 256 = 17152 dword4s
    zbase[i] = (u32x4){0u, 0u, 0u, 0u};
  }
}

// ---------------- fused front: z=h@V (bf16 MFMA) + exact-fp32 router --------
// BM=32, BN=128, BK=64. grid 1024, 4 waves (32x32 each), 3 blocks/CU (~47KB).
// Paired-XCD swizzle: the two n-halves of an m-tile land on the same XCD.
__global__ __launch_bounds__(256, 3) void k_front(
    const float* __restrict__ h, const ushort_t* __restrict__ Vt,
    const float* __restrict__ VeffT, const float* __restrict__ br,
    ushort_t* __restrict__ zb, int* __restrict__ topi, float* __restrict__ topw,
    int* __restrict__ ctrl) {
  __shared__ ushort_t As[2][32 * 72];     // padded stride 72 (2-way, free)
  __shared__ ushort_t Bs[2][128 * 64];    // swizzled
  __shared__ float Vs[2][512];            // VeffT chunk [8][64]
  __shared__ int lcnt[8];
  int hw = blockIdx.x;
  int swz = (hw & 7) * 128 + (hw >> 3);   // 1024 = 8*128, bijective
  int mt = swz >> 1, nt = swz & 1;
  int m0 = mt * 32, n0 = nt * 128;
  int t = threadIdx.x;
  int lane = t & 63, wave = t >> 6;
  int ln = lane & 15, hi = lane >> 4;
  const int xo = (ln & 7) << 3;
  int arow = t >> 3, koff = (t & 7) * 8;
  const float* aptr = h + (size_t)(m0 + arow) * DD + koff;
  if (t < 8) lcnt[t] = 0;

  f32x4 acc[2][2];
  #pragma unroll
  for (int i = 0; i < 2; ++i)
    #pragma unroll
    for (int j = 0; j < 2; ++j) acc[i][j] = (f32x4){0.f, 0.f, 0.f, 0.f};
  float racc[8] = {0, 0, 0, 0, 0, 0, 0, 0};

  f32x4 pc0, pc1, pn0, pn1;
  {  // prologue k=0
    pc0 = ((const f32x4*)aptr)[0];
    pc1 = ((const f32x4*)aptr)[1];
    #pragma unroll
    for (int u = 0; u < 4; ++u) {
      int idx = u * 256 + t;
      gll16(Vt + (size_t)(n0 + (idx >> 3)) * DD + SWZ8(idx), &Bs[0][idx * 8]);
    }
    if (nt == 0 && t < 128) gll16(VeffT + (size_t)(t >> 4) * DD + (t & 15) * 4, &Vs[0][t * 4]);
    *(u16x8*)&As[0][arow * 72 + koff] = pack8(pc0, pc1);
  }
  __syncthreads();

  for (int s = 0; s < 32; ++s) {
    int cb = s & 1, xb = cb ^ 1;
    int k1 = (s + 1) * 64;
    if (s < 31) {
      pn0 = ((const f32x4*)(aptr + k1))[0];
      pn1 = ((const f32x4*)(aptr + k1))[1];
      #pragma unroll
      for (int u = 0; u < 4; ++u) {
        int idx = u * 256 + t;
        gll16(Vt + (size_t)(n0 + (idx >> 3)) * DD + k1 + SWZ8(idx), &Bs[xb][idx * 8]);
      }
      if (nt == 0 && t < 128)
        gll16(VeffT + (size_t)(t >> 4) * DD + k1 + (t & 15) * 4, &Vs[xb][t * 4]);
    }
    // exact-fp32 router partial on current chunk (nt==0 blocks only)
    if (nt == 0) {
      const f32x4* vsb = (const f32x4*)&Vs[cb][0];
      #pragma unroll
      for (int e = 0; e < 8; ++e) {
        f32x4 v0 = vsb[(e * 64 + koff) >> 2];
        f32x4 v1 = vsb[((e * 64 + koff) >> 2) + 1];
        racc[e] += pc0.x * v0.x + pc0.y * v0.y + pc0.z * v0.z + pc0.w * v0.w +
                   pc1.x * v1.x + pc1.y * v1.y + pc1.z * v1.z + pc1.w * v1.w;
      }
    }
    #pragma unroll
    for (int ks = 0; ks < 2; ++ks) {
      s16x8 af[2], bq[2];
      #pragma unroll
      for (int i = 0; i < 2; ++i)
        af[i] = *(const s16x8*)&As[cb][(i * 16 + ln) * 72 + ks * 32 + hi * 8];
      #pragma unroll
      for (int j = 0; j < 2; ++j)
        bq[j] = *(const s16x8*)&Bs[cb][(wave * 32 + j * 16 + ln) * 64 + ((ks * 32 + hi * 8) ^ xo)];
      #pragma unroll
      for (int i = 0; i < 2; ++i)
        #pragma unroll
        for (int j = 0; j < 2; ++j)
          acc[i][j] = __builtin_amdgcn_mfma_f32_16x16x32_bf16(af[i], bq[j], acc[i][j], 0, 0, 0);
    }
    if (s < 31) {
      *(u16x8*)&As[xb][arow * 72 + koff] = pack8(pn0, pn1);
      pc0 = pn0; pc1 = pn1;
    }
    __syncthreads();
  }

  // z write
  #pragma unroll
  for (int i = 0; i < 2; ++i)
    #pragma unroll
    for (int j = 0; j < 2; ++j)
      #pragma unroll
      for (int r = 0; r < 4; ++r) {
        int row = m0 + i * 16 + hi * 4 + r;
        int col = n0 + wave * 32 + j * 16 + ln;
        zb[(size_t)row * RR + col] = f2bf(acc[i][j][r]);
      }

  if (nt == 0) {
    // router: reduce over the 8 lanes sharing a row, then top-2
    #pragma unroll
    for (int e = 0; e < 8; ++e) {
      racc[e] += __shfl_xor(racc[e], 1, 64);
      racc[e] += __shfl_xor(racc[e], 2, 64);
      racc[e] += __shfl_xor(racc[e], 4, 64);
    }
    if ((t & 7) == 0) {
      int token = m0 + arow;
      f32x4 br0 = ((const f32x4*)br)[0], br1 = ((const f32x4*)br)[1];
      float l[8] = {racc[0] + br0.x, racc[1] + br0.y, racc[2] + br0.z, racc[3] + br0.w,
                    racc[4] + br1.x, racc[5] + br1.y, racc[6] + br1.z, racc[7] + br1.w};
      float best = -1e30f; int bi = 0;
      #pragma unroll
      for (int e = 0; e < 8; ++e) if (l[e] > best) { best = l[e]; bi = e; }
      float sec = -1e30f; int si = 0;
      #pragma unroll
      for (int e = 0; e < 8; ++e) if (e != bi && l[e] > sec) { sec = l[e]; si = e; }
      float w0 = 1.f / (1.f + expf(sec - best));
      topi[token * 2 + 0] = bi; topi[token * 2 + 1] = si;
      topw[token * 2 + 0] = w0; topw[token * 2 + 1] = 1.f - w0;
      atomicAdd(&lcnt[bi], 1);
      atomicAdd(&lcnt[si], 1);
    }
    __syncthreads();
    if (t < 8) atomicAdd(&ctrl[t], lcnt[t]);
  }
}

// ---------------- bases: padded per-expert segments (parallel) --------------
// ctrl layout (ints): [0..7]=counts [8..15]=gcursor [16..16+264)=seg2expert
__global__ __launch_bounds__(256) void k_bases(int* ctrl) {
  __shared__ int sb[8], se[8];
  int t = threadIdx.x;
  if (t < 8) {
    int segs = (ctrl[t] + 127) >> 7;
    int scan = segs;
    #pragma unroll
    for (int o = 1; o < 8; o <<= 1) {
      int u2 = __shfl_up(scan, o, 64);
      if (t >= o) scan += u2;
    }
    int start = scan - segs;          // exclusive scan, segment units
    ctrl[8 + t] = start << 7;         // pair-slot cursor base
    sb[t] = start; se[t] = scan;
  }
  __syncthreads();
  for (int sg = t; sg < NSEG_MAX; sg += 256) {
    int e = -1;
    #pragma unroll
    for (int k = 0; k < 8; ++k)
      if (sg >= sb[k] && sg < se[k]) e = k;
    ctrl[16 + sg] = e;
  }
}

// ---------------- scatter tokens into per-expert pair lists + inverse map ---
__global__ __launch_bounds__(256) void k_scatter(const int* topi, const float* topw,
                                                 int* ctrl, int* pair_t, float* pair_w,
                                                 int* inv) {
  __shared__ int lcnt[8], lbase[8];
  int t = threadIdx.x;
  if (t < 8) lcnt[t] = 0;
  __syncthreads();
  int slot = blockIdx.x * 256 + t;
  int e = topi[slot];
  float wv = topw[slot];
  int lp = atomicAdd(&lcnt[e], 1);
  __syncthreads();
  if (t < 8) lbase[t] = atomicAdd(&ctrl[8 + t], lcnt[t]);
  __syncthreads();
  int p = lbase[e] + lp;
  pair_t[p] = slot >> 1;
  pair_w[p] = wv;
  inv[slot] = p;
}

// swizzled [128][64] tile reads (xo = (ln&7)<<3 must be defined)
#define GEMM_COMPUTE(AS, BS)                                                          \
  _Pragma("unroll")                                                                   \
  for (int ks = 0; ks < 2; ++ks) {                                                    \
    s16x8 af[4], bq[4];                                                               \
    _Pragma("unroll")                                                                 \
    for (int i = 0; i < 4; ++i)                                                       \
      af[i] = *(const s16x8*)&AS[(wr * 64 + i * 16 + ln) * 64 + ((ks * 32 + hi * 8) ^ xo)]; \
    _Pragma("unroll")                                                                 \
    for (int j = 0; j < 4; ++j)                                                       \
      bq[j] = *(const s16x8*)&BS[(wc * 64 + j * 16 + ln) * 64 + ((ks * 32 + hi * 8) ^ xo)]; \
    _Pragma("unroll")                                                                 \
    for (int i = 0; i < 4; ++i)                                                       \
      _Pragma("unroll")                                                               \
      for (int j = 0; j < 4; ++j)                                                     \
        acc[i][j] = __builtin_amdgcn_mfma_f32_16x16x32_bf16(af[i], bq[j], acc[i][j], 0, 0, 0); \
  }

// ---------------- e1: hidden = gelu(gather(zb) @ W1[e] + b1) ---------------
__global__ __launch_bounds__(256, 2) void k_e1(const ushort_t* zb, const ushort_t* W1t,
                                               const float* b1, const int* ctrl,
                                               const int* pair_t, ushort_t* hidden) {
  __shared__ ushort_t As[2][8192];
  __shared__ ushort_t Bs[2][8192];
  __shared__ int pt[128];
  int sg = blockIdx.x >> 2, nt = blockIdx.x & 3;
  int e = ctrl[16 + sg];
  if (e < 0) return;
  int t = threadIdx.x;
  if (t < 128) pt[t] = pair_t[sg * 128 + t];
  __syncthreads();
  int n0 = nt * 128;
  const ushort_t* Bbase = W1t + (size_t)e * HH * RR;
  int lane = t & 63, wave = t >> 6;
  int wr = wave >> 1, wc = wave & 1;
  int ln = lane & 15, hi = lane >> 4;
  const int xo = (ln & 7) << 3;

  f32x4 acc[4][4];
  #pragma unroll
  for (int i = 0; i < 4; ++i)
    #pragma unroll
    for (int j = 0; j < 4; ++j) acc[i][j] = (f32x4){0.f, 0.f, 0.f, 0.f};

  #pragma unroll
  for (int u = 0; u < 4; ++u) {
    int idx = u * 256 + t;
    gll16(zb + (size_t)pt[idx >> 3] * RR + SWZ8(idx), &As[0][idx * 8]);
    gll16(Bbase + (size_t)(n0 + (idx >> 3)) * RR + SWZ8(idx), &Bs[0][idx * 8]);
  }
  __syncthreads();
  for (int s = 0; s < 4; ++s) {
    int cb = s & 1, xb = cb ^ 1;
    if (s < 3) {
      int k1 = (s + 1) * 64;
      #pragma unroll
      for (int u = 0; u < 4; ++u) {
        int idx = u * 256 + t;
        gll16(zb + (size_t)pt[idx >> 3] * RR + k1 + SWZ8(idx), &As[xb][idx * 8]);
        gll16(Bbase + (size_t)(n0 + (idx >> 3)) * RR + k1 + SWZ8(idx), &Bs[xb][idx * 8]);
      }
    }
    GEMM_COMPUTE(As[cb], Bs[cb]);
    __syncthreads();
  }
  #pragma unroll
  for (int i = 0; i < 4; ++i)
    #pragma unroll
    for (int j = 0; j < 4; ++j)
      #pragma unroll
      for (int r = 0; r < 4; ++r) {
        int pl = wr * 64 + i * 16 + hi * 4 + r;
        int col = n0 + wc * 64 + j * 16 + ln;
        float v = acc[i][j][r] + b1[e * HH + col];
        float g = 0.5f * v * (1.f + erff(v * 0.70710678118654752f));
        hidden[(size_t)(sg * 128 + pl) * HH + col] = f2bf(g);
      }
}

// ---------------- e2: eout[p] = w_p * (hidden @ W2[e] + b2)  (bf16 stores) --
__global__ __launch_bounds__(256, 2) void k_e2(const ushort_t* hidden, const ushort_t* W2t,
                                               const float* b2, const int* ctrl,
                                               const int* pair_t, const float* pair_w,
                                               ushort_t* eout) {
  __shared__ ushort_t As[2][8192];
  __shared__ ushort_t Bs[2][8192];
  __shared__ float pw[128];
  int sg = blockIdx.x >> 1, nt = blockIdx.x & 1;
  int e = ctrl[16 + sg];
  if (e < 0) return;
  int t = threadIdx.x;
  if (t < 128) pw[t] = pair_w[sg * 128 + t];
  __syncthreads();
  int n0 = nt * 128;
  const ushort_t* Abase = hidden + (size_t)sg * 128 * HH;
  const ushort_t* Bbase = W2t + (size_t)e * RR * HH;
  int lane = t & 63, wave = t >> 6;
  int wr = wave >> 1, wc = wave & 1;
  int ln = lane & 15, hi = lane >> 4;
  const int xo = (ln & 7) << 3;

  f32x4 acc[4][4];
  #pragma unroll
  for (int i = 0; i < 4; ++i)
    #pragma unroll
    for (int j = 0; j < 4; ++j) acc[i][j] = (f32x4){0.f, 0.f, 0.f, 0.f};

  #pragma unroll
  for (int u = 0; u < 4; ++u) {
    int idx = u * 256 + t;
    gll16(Abase + (size_t)(idx >> 3) * HH + SWZ8(idx), &As[0][idx * 8]);
    gll16(Bbase + (size_t)(n0 + (idx >> 3)) * HH + SWZ8(idx), &Bs[0][idx * 8]);
  }
  __syncthreads();
  for (int s = 0; s < 8; ++s) {
    int cb = s & 1, xb = cb ^ 1;
    if (s < 7) {
      int k1 = (s + 1) * 64;
      #pragma unroll
      for (int u = 0; u < 4; ++u) {
        int idx = u * 256 + t;
        gll16(Abase + (size_t)(idx >> 3) * HH + k1 + SWZ8(idx), &As[xb][idx * 8]);
        gll16(Bbase + (size_t)(n0 + (idx >> 3)) * HH + k1 + SWZ8(idx), &Bs[xb][idx * 8]);
      }
    }
    GEMM_COMPUTE(As[cb], Bs[cb]);
    __syncthreads();
  }
  #pragma unroll
  for (int i = 0; i < 4; ++i)
    #pragma unroll
    for (int j = 0; j < 4; ++j)
      #pragma unroll
      for (int r = 0; r < 4; ++r) {
        int pl = wr * 64 + i * 16 + hi * 4 + r;
        int col = n0 + wc * 64 + j * 16 + ln;
        float v = acc[i][j][r] + b2[e * RR + col];
        eout[(size_t)(sg * 128 + pl) * RR + col] = f2bf(pw[pl] * v);
      }
}

// ---------------- final: z_final = 0.75*z + 0.25*(eout0+eout1) -------------
__global__ __launch_bounds__(256) void k_final(const ushort_t* __restrict__ zb,
                                               const ushort_t* __restrict__ eout,
                                               const int* __restrict__ inv,
                                               const float* __restrict__ Uh,
                                               const float* __restrict__ bh,
                                               ushort_t* __restrict__ zb2,
                                               float* __restrict__ phalt) {
  __shared__ float luh[256];
  int t = threadIdx.x;
  if (t < 64) ((f32x4*)luh)[t] = ((const f32x4*)Uh)[t];
  __syncthreads();
  int tok = blockIdx.x * 64 + (t >> 2), q = t & 3;
  int i0 = inv[tok * 2], i1 = inv[tok * 2 + 1];
  const u16x8* z8 = (const u16x8*)(zb + (size_t)tok * RR + q * 64);
  const u16x8* ea = (const u16x8*)(eout + (size_t)i0 * RR + q * 64);
  const u16x8* eb = (const u16x8*)(eout + (size_t)i1 * RR + q * 64);
  ushort_t* o = zb2 + (size_t)tok * RR + q * 64;
  float acc = 0.f;
  #pragma unroll
  for (int it = 0; it < 8; ++it) {
    u16x8 zv = z8[it], av = ea[it], bv = eb[it];
    u16x8 pk;
    #pragma unroll
    for (int j = 0; j < 8; ++j) {
      float zf = 0.75f * bf2f(zv[j]) + 0.25f * (bf2f(av[j]) + bf2f(bv[j]));
      acc += zf * luh[q * 64 + it * 8 + j];
      pk[j] = f2bf(zf);
    }
    *(u16x8*)(o + it * 8) = pk;
  }
  acc += __shfl_xor(acc, 1, 64);
  acc += __shfl_xor(acc, 2, 64);
  if (q == 0) phalt[tok] = 1.f / (1.f + expf(-(acc + bh[0])));
}

// ---------------- gemm_u: h_new[T][D] = zb2 @ U ----------------------------
__global__ __launch_bounds__(256, 2) void k_gemm_u(const ushort_t* zb2, const ushort_t* Ut,
                                                   float* outp) {
  __shared__ ushort_t As[2][8192];
  __shared__ ushort_t Bs[2][8192];
  int hw = blockIdx.x;
  int bid = (hw & 7) * 256 + (hw >> 3);    // XCD swizzle (2048 = 8*256)
  int mt = bid >> 4, nt = bid & 15;
  int m0 = mt * 128, n0 = nt * 128;
  int t = threadIdx.x;
  int lane = t & 63, wave = t >> 6;
  int wr = wave >> 1, wc = wave & 1;
  int ln = lane & 15, hi = lane >> 4;
  const int xo = (ln & 7) << 3;

  f32x4 acc[4][4];
  #pragma unroll
  for (int i = 0; i < 4; ++i)
    #pragma unroll
    for (int j = 0; j < 4; ++j) acc[i][j] = (f32x4){0.f, 0.f, 0.f, 0.f};

  #pragma unroll
  for (int u = 0; u < 4; ++u) {
    int idx = u * 256 + t;
    gll16(zb2 + (size_t)(m0 + (idx >> 3)) * RR + SWZ8(idx), &As[0][idx * 8]);
    gll16(Ut + (size_t)(n0 + (idx >> 3)) * RR + SWZ8(idx), &Bs[0][idx * 8]);
  }
  __syncthreads();
  for (int s = 0; s < 4; ++s) {
    int cb = s & 1, xb = cb ^ 1;
    if (s < 3) {
      int k1 = (s + 1) * 64;
      #pragma unroll
      for (int u = 0; u < 4; ++u) {
        int idx = u * 256 + t;
        gll16(zb2 + (size_t)(m0 + (idx >> 3)) * RR + k1 + SWZ8(idx), &As[xb][idx * 8]);
        gll16(Ut + (size_t)(n0 + (idx >> 3)) * RR + k1 + SWZ8(idx), &Bs[xb][idx * 8]);
      }
    }
    GEMM_COMPUTE(As[cb], Bs[cb]);
    __syncthreads();
  }
  #pragma unroll
  for (int i = 0; i < 4; ++i)
    #pragma unroll
    for (int j = 0; j < 4; ++j)
      #pragma unroll
      for (int r = 0; r < 4; ++r) {
        int row = m0 + wr * 64 + i * 16 + hi * 4 + r;
        int col = n0 + wc * 64 + j * 16 + ln;
        outp[(size_t)row * DD + col] = acc[i][j][r];
      }
}

// ---------------------------------------------------------------------------
extern "C" void kernel_launch(void* const* d_in, const int* in_sizes, int n_in,
                              void* d_out, int out_size, void* d_ws, size_t ws_size,
                              hipStream_t stream) {
  (void)in_sizes; (void)n_in; (void)out_size;
  const float* h  = (const float*)d_in[0];
  const float* V  = (const float*)d_in[1];
  const float* U  = (const float*)d_in[2];
  const float* Wr = (const float*)d_in[3];
  const float* br = (const float*)d_in[4];
  const float* W1 = (const float*)d_in[5];
  const float* b1 = (const float*)d_in[6];
  const float* W2 = (const float*)d_in[7];
  const float* b2 = (const float*)d_in[8];
  const float* Wh = (const float*)d_in[9];
  const float* bh = (const float*)d_in[10];
  float* outp = (float*)d_out;
  char* w = (char*)d_ws;

  constexpr size_t OFF_VT    = 0;          // 1 MB   Vt   [256][2048] bf16
  constexpr size_t OFF_UT    = 1048576;    // 1 MB   Ut   [2048][256] bf16
  constexpr size_t OFF_W1T   = 2097152;    // 2 MB   W1t  [8][512][256] bf16
  constexpr size_t OFF_W2T   = 4194304;    // 2 MB   W2t  [8][256][512] bf16
  constexpr size_t OFF_VEFFT = 6291456;    // 64 KB  VeffT [8][2048] f32
  constexpr size_t OFF_UHV   = 6356992;    // 4 KB   Uh [256] f32
  constexpr size_t OFF_TOPI  = 6361088;    // 128 KB
  constexpr size_t OFF_TOPW  = 6492160;    // 128 KB
  constexpr size_t OFF_INV   = 6623232;    // 128 KB
  constexpr size_t OFF_CTRL  = 6754304;    // 4 KB   (zeroed by k_prep)
  constexpr size_t OFF_PT    = 6758400;    // 132 KB (zeroed by k_prep)
  constexpr size_t OFF_PW    = 6893568;    // 132 KB (zeroed by k_prep)
  constexpr size_t OFF_ZB    = 7028736;    // 8 MB   zb [16384][256] bf16
  constexpr size_t OFF_EOUT  = 15417344;   // 16.5MB eout [33792][256] bf16
  constexpr size_t OFF_HID   = 32718848;   // 33 MB  hidden [33792][512] bf16
  constexpr size_t OFF_ZB2   = OFF_HID;    // aliases hidden (dead after e2)
  constexpr size_t WS_NEED   = 67321856;
  if (ws_size < WS_NEED) return;

  ushort_t* Vt    = (ushort_t*)(w + OFF_VT);
  ushort_t* Ut    = (ushort_t*)(w + OFF_UT);
  ushort_t* W1t   = (ushort_t*)(w + OFF_W1T);
  ushort_t* W2t   = (ushort_t*)(w + OFF_W2T);
  float*    VeffT = (float*)(w + OFF_VEFFT);
  float*    Uh    = (float*)(w + OFF_UHV);
  int*      topi  = (int*)(w + OFF_TOPI);
  float*    topw  = (float*)(w + OFF_TOPW);
  int*      inv   = (int*)(w + OFF_INV);
  int*      ctrl  = (int*)(w + OFF_CTRL);
  int*      pair_t= (int*)(w + OFF_PT);
  float*    pair_w= (float*)(w + OFF_PW);
  ushort_t* zb    = (ushort_t*)(w + OFF_ZB);
  ushort_t* eout  = (ushort_t*)(w + OFF_EOUT);
  ushort_t* hidden= (ushort_t*)(w + OFF_HID);
  ushort_t* zb2   = (ushort_t*)(w + OFF_ZB2);

  // k_prep also zeroes [OFF_CTRL, OFF_ZB) — 17152 dword4s (ctrl + pair lists)
  k_prep<<<3211, 256, 0, stream>>>(V, U, W1, W2, Wr, Wh, Vt, Ut, W1t, W2t,
                                   VeffT, Uh, (u32x4*)(w + OFF_CTRL));
  k_front<<<1024, 256, 0, stream>>>(h, Vt, VeffT, br, zb, topi, topw, ctrl);
  k_bases<<<1, 256, 0, stream>>>(ctrl);
  k_scatter<<<128, 256, 0, stream>>>(topi, topw, ctrl, pair_t, pair_w, inv);
  k_e1<<<NSEG_MAX * 4, 256, 0, stream>>>(zb, W1t, b1, ctrl, pair_t, hidden);
  k_e2<<<NSEG_MAX * 2, 256, 0, stream>>>(hidden, W2t, b2, ctrl, pair_t, pair_w, eout);
  k_final<<<256, 256, 0, stream>>>(zb, eout, inv, Uh, bh, zb2, outp + (size_t)TK * DD);
  k_gemm_u<<<2048, 256, 0, stream>>>(zb2, Ut, outp);
}

// Round 7
// 208.546 us; speedup vs baseline: 1.1557x; 1.1557x over previous
//
#include <hip/hip_runtime.h>
#include <stdint.h>
#include <math.h>

#define TK 16384
#define DD 2048
#define RR 256
#define EE 8
#define HH 512
#define NSEG_MAX 264
#define NPAIR_MAX (NSEG_MAX * 128)

typedef __attribute__((ext_vector_type(4))) float f32x4;
typedef __attribute__((ext_vector_type(8))) short s16x8;
typedef __attribute__((ext_vector_type(8))) unsigned short u16x8;
typedef __attribute__((ext_vector_type(4))) unsigned u32x4;
typedef unsigned short ushort_t;

__device__ inline unsigned short f2bf(float f) {
  union { float f; unsigned u; } v; v.f = f;
  unsigned r = v.u + 0x7fffu + ((v.u >> 16) & 1u);
  return (unsigned short)(r >> 16);
}
__device__ inline float bf2f(ushort_t u) {
  union { unsigned u; float f; } v; v.u = ((unsigned)u) << 16; return v.f;
}

__device__ inline void gll16(const void* g, void* l) {
  __builtin_amdgcn_global_load_lds(
      (const __attribute__((address_space(1))) void*)g,
      (__attribute__((address_space(3))) void*)l, 16, 0, 0);
}

__device__ inline u16x8 pack8(f32x4 a, f32x4 b) {
  u16x8 r;
  r[0] = f2bf(a.x); r[1] = f2bf(a.y); r[2] = f2bf(a.z); r[3] = f2bf(a.w);
  r[4] = f2bf(b.x); r[5] = f2bf(b.y); r[6] = f2bf(b.z); r[7] = f2bf(b.w);
  return r;
}

// LDS XOR-swizzle: LDS[row][slot] = G[row][slot ^ (row&7)] (8-elem bf16 slots)
#define SWZ8(idx) (((idx & 7) ^ ((idx >> 3) & 7)) * 8)

// ---------------- fused prep: 4 transposes + VeffT + Uh + ctrl/pair zeroing -
__global__ __launch_bounds__(256) void k_prep(
    const float* __restrict__ V, const float* __restrict__ U,
    const float* __restrict__ W1, const float* __restrict__ W2,
    const float* __restrict__ Wr, const float* __restrict__ Wh,
    ushort_t* __restrict__ Vt, ushort_t* __restrict__ Ut,
    ushort_t* __restrict__ W1t, ushort_t* __restrict__ W2t,
    float* __restrict__ VeffT, float* __restrict__ Uh,
    u32x4* __restrict__ zbase) {
  __shared__ float sm[2112];
  int b = blockIdx.x, t = threadIdx.x;
  if (b < 3072) {
    const float* src; ushort_t* dst; int nr, nc, c0, r0;
    if (b < 512)       { src = V; dst = Vt; nr = 2048; nc = 256;
                         c0 = (b & 7) * 32; r0 = (b >> 3) * 32; }
    else if (b < 1024) { int bx = b - 512; src = U; dst = Ut; nr = 256; nc = 2048;
                         c0 = (bx & 63) * 32; r0 = (bx >> 6) * 32; }
    else if (b < 2048) { int bx = b - 1024; int s = bx >> 7; bx &= 127;
                         src = W1 + (size_t)s * 131072; dst = W1t + (size_t)s * 131072;
                         nr = 256; nc = 512; c0 = (bx & 15) * 32; r0 = (bx >> 4) * 32; }
    else               { int bx = b - 2048; int s = bx >> 7; bx &= 127;
                         src = W2 + (size_t)s * 131072; dst = W2t + (size_t)s * 131072;
                         nr = 512; nc = 256; c0 = (bx & 7) * 32; r0 = (bx >> 3) * 32; }
    int tx = t & 31, ty = t >> 5;
    #pragma unroll
    for (int i = 0; i < 32; i += 8)
      sm[(ty + i) * 33 + tx] = src[(size_t)(r0 + ty + i) * nc + c0 + tx];
    __syncthreads();
    #pragma unroll
    for (int i = 0; i < 32; i += 8)
      dst[(size_t)(c0 + ty + i) * nr + r0 + tx] = f2bf(sm[tx * 33 + ty + i]);
  } else if (b < 3080) {
    #pragma unroll
    for (int i = 0; i < 8; ++i) sm[i * 256 + t] = Wr[i * 256 + t];
    __syncthreads();
    int d = (b - 3072) * 256 + t;
    float a[8] = {0, 0, 0, 0, 0, 0, 0, 0};
    const float* vrow = V + (size_t)d * RR;
    for (int r = 0; r < RR; r += 4) {
      f32x4 v = *(const f32x4*)(vrow + r);
      #pragma unroll
      for (int e = 0; e < 8; ++e)
        a[e] += v.x * sm[r * 8 + e] + v.y * sm[(r + 1) * 8 + e] +
                v.z * sm[(r + 2) * 8 + e] + v.w * sm[(r + 3) * 8 + e];
    }
    #pragma unroll
    for (int e = 0; e < 8; ++e) VeffT[(size_t)e * DD + d] = a[e];
  } else if (b < 3144) {
    int wave = t >> 6, lane = t & 63;
    int r = (b - 3080) * 4 + wave;
    const f32x4* u4 = (const f32x4*)(U + (size_t)r * DD);
    const f32x4* w4 = (const f32x4*)Wh;
    float acc = 0.f;
    #pragma unroll
    for (int it = 0; it < 8; ++it) {
      f32x4 a = u4[it * 64 + lane], bb = w4[it * 64 + lane];
      acc += a.x * bb.x + a.y * bb.y + a.z * bb.z + a.w * bb.w;
    }
    #pragma unroll
    for (int o = 32; o; o >>= 1) acc += __shfl_down(acc, o, 64);
    if (lane == 0) Uh[r] = acc;
  } else {
    int i = (b - 3144) * 256 + t;      // 67 blocks * 256 = 17152 dword4s
    zbase[i] = (u32x4){0u, 0u, 0u, 0u};
  }
}

// ---------------- fused front (round-5 verified): z=h@V + exact-fp32 router -
// tile 32 rows x 256 cols, K-step 64, 4 waves (each 32x64), grid 512.
__global__ __launch_bounds__(256, 2) void k_front(
    const float* __restrict__ h, const ushort_t* __restrict__ Vt,
    const float* __restrict__ VeffT, const float* __restrict__ br,
    ushort_t* __restrict__ zb, int* __restrict__ topi, float* __restrict__ topw,
    int* __restrict__ ctrl) {
  __shared__ ushort_t As[2][32 * 72];     // padded stride 72 (2-way, free)
  __shared__ ushort_t Bs[2][256 * 64];    // swizzled
  __shared__ float Vs[2][512];            // VeffT chunk [8][64]
  __shared__ int lcnt[8];
  int t = threadIdx.x;
  int m0 = blockIdx.x * 32;
  int lane = t & 63, wave = t >> 6;
  int ln = lane & 15, hi = lane >> 4;
  const int xo = (ln & 7) << 3;
  int arow = t >> 3, koff = (t & 7) * 8;
  const float* aptr = h + (size_t)(m0 + arow) * DD + koff;
  if (t < 8) lcnt[t] = 0;

  f32x4 acc[2][4];
  #pragma unroll
  for (int i = 0; i < 2; ++i)
    #pragma unroll
    for (int j = 0; j < 4; ++j) acc[i][j] = (f32x4){0.f, 0.f, 0.f, 0.f};
  float racc[8] = {0, 0, 0, 0, 0, 0, 0, 0};

  f32x4 pc0, pc1, pn0, pn1;
  {  // prologue k=0
    pc0 = ((const f32x4*)aptr)[0];
    pc1 = ((const f32x4*)aptr)[1];
    #pragma unroll
    for (int u = 0; u < 8; ++u) {
      int idx = u * 256 + t;
      gll16(Vt + (size_t)(idx >> 3) * DD + SWZ8(idx), &Bs[0][idx * 8]);
    }
    if (t < 128) gll16(VeffT + (size_t)(t >> 4) * DD + (t & 15) * 4, &Vs[0][t * 4]);
    *(u16x8*)&As[0][arow * 72 + koff] = pack8(pc0, pc1);
  }
  __syncthreads();

  for (int s = 0; s < 32; ++s) {
    int cb = s & 1, xb = cb ^ 1;
    int k1 = (s + 1) * 64;
    if (s < 31) {
      pn0 = ((const f32x4*)(aptr + k1))[0];
      pn1 = ((const f32x4*)(aptr + k1))[1];
      #pragma unroll
      for (int u = 0; u < 8; ++u) {
        int idx = u * 256 + t;
        gll16(Vt + (size_t)(idx >> 3) * DD + k1 + SWZ8(idx), &Bs[xb][idx * 8]);
      }
      if (t < 128) gll16(VeffT + (size_t)(t >> 4) * DD + k1 + (t & 15) * 4, &Vs[xb][t * 4]);
    }
    // exact-fp32 router partial on current chunk
    {
      const f32x4* vsb = (const f32x4*)&Vs[cb][0];
      #pragma unroll
      for (int e = 0; e < 8; ++e) {
        f32x4 v0 = vsb[(e * 64 + koff) >> 2];
        f32x4 v1 = vsb[((e * 64 + koff) >> 2) + 1];
        racc[e] += pc0.x * v0.x + pc0.y * v0.y + pc0.z * v0.z + pc0.w * v0.w +
                   pc1.x * v1.x + pc1.y * v1.y + pc1.z * v1.z + pc1.w * v1.w;
      }
    }
    #pragma unroll
    for (int ks = 0; ks < 2; ++ks) {
      s16x8 af[2], bq[4];
      #pragma unroll
      for (int i = 0; i < 2; ++i)
        af[i] = *(const s16x8*)&As[cb][(i * 16 + ln) * 72 + ks * 32 + hi * 8];
      #pragma unroll
      for (int j = 0; j < 4; ++j)
        bq[j] = *(const s16x8*)&Bs[cb][(wave * 64 + j * 16 + ln) * 64 + ((ks * 32 + hi * 8) ^ xo)];
      #pragma unroll
      for (int i = 0; i < 2; ++i)
        #pragma unroll
        for (int j = 0; j < 4; ++j)
          acc[i][j] = __builtin_amdgcn_mfma_f32_16x16x32_bf16(af[i], bq[j], acc[i][j], 0, 0, 0);
    }
    if (s < 31) {
      *(u16x8*)&As[xb][arow * 72 + koff] = pack8(pn0, pn1);
      pc0 = pn0; pc1 = pn1;
    }
    __syncthreads();
  }

  // z write
  #pragma unroll
  for (int i = 0; i < 2; ++i)
    #pragma unroll
    for (int j = 0; j < 4; ++j)
      #pragma unroll
      for (int r = 0; r < 4; ++r) {
        int row = m0 + i * 16 + hi * 4 + r;
        int col = wave * 64 + j * 16 + ln;
        zb[(size_t)row * RR + col] = f2bf(acc[i][j][r]);
      }

  // router: reduce over the 8 lanes sharing a row, then top-2
  #pragma unroll
  for (int e = 0; e < 8; ++e) {
    racc[e] += __shfl_xor(racc[e], 1, 64);
    racc[e] += __shfl_xor(racc[e], 2, 64);
    racc[e] += __shfl_xor(racc[e], 4, 64);
  }
  if ((t & 7) == 0) {
    int token = m0 + arow;
    f32x4 br0 = ((const f32x4*)br)[0], br1 = ((const f32x4*)br)[1];
    float l[8] = {racc[0] + br0.x, racc[1] + br0.y, racc[2] + br0.z, racc[3] + br0.w,
                  racc[4] + br1.x, racc[5] + br1.y, racc[6] + br1.z, racc[7] + br1.w};
    float best = -1e30f; int bi = 0;
    #pragma unroll
    for (int e = 0; e < 8; ++e) if (l[e] > best) { best = l[e]; bi = e; }
    float sec = -1e30f; int si = 0;
    #pragma unroll
    for (int e = 0; e < 8; ++e) if (e != bi && l[e] > sec) { sec = l[e]; si = e; }
    float w0 = 1.f / (1.f + expf(sec - best));
    topi[token * 2 + 0] = bi; topi[token * 2 + 1] = si;
    topw[token * 2 + 0] = w0; topw[token * 2 + 1] = 1.f - w0;
    atomicAdd(&lcnt[bi], 1);
    atomicAdd(&lcnt[si], 1);
  }
  __syncthreads();
  if (t < 8) atomicAdd(&ctrl[t], lcnt[t]);
}

// ---------------- bases: padded per-expert segments (parallel) --------------
__global__ __launch_bounds__(256) void k_bases(int* ctrl) {
  __shared__ int sb[8], se[8];
  int t = threadIdx.x;
  if (t < 8) {
    int segs = (ctrl[t] + 127) >> 7;
    int scan = segs;
    #pragma unroll
    for (int o = 1; o < 8; o <<= 1) {
      int u2 = __shfl_up(scan, o, 64);
      if (t >= o) scan += u2;
    }
    int start = scan - segs;          // exclusive scan, segment units
    ctrl[8 + t] = start << 7;         // pair-slot cursor base
    sb[t] = start; se[t] = scan;
  }
  __syncthreads();
  for (int sg = t; sg < NSEG_MAX; sg += 256) {
    int e = -1;
    #pragma unroll
    for (int k = 0; k < 8; ++k)
      if (sg >= sb[k] && sg < se[k]) e = k;
    ctrl[16 + sg] = e;
  }
}

// ---------------- scatter tokens into per-expert pair lists + inverse map ---
__global__ __launch_bounds__(256) void k_scatter(const int* topi, const float* topw,
                                                 int* ctrl, int* pair_t, float* pair_w,
                                                 int* inv) {
  __shared__ int lcnt[8], lbase[8];
  int t = threadIdx.x;
  if (t < 8) lcnt[t] = 0;
  __syncthreads();
  int slot = blockIdx.x * 256 + t;
  int e = topi[slot];
  float wv = topw[slot];
  int lp = atomicAdd(&lcnt[e], 1);
  __syncthreads();
  if (t < 8) lbase[t] = atomicAdd(&ctrl[8 + t], lcnt[t]);
  __syncthreads();
  int p = lbase[e] + lp;
  pair_t[p] = slot >> 1;
  pair_w[p] = wv;
  inv[slot] = p;
}

// swizzled [128][64] tile reads (xo = (ln&7)<<3 must be defined)
#define GEMM_COMPUTE(AS, BS)                                                          \
  _Pragma("unroll")                                                                   \
  for (int ks = 0; ks < 2; ++ks) {                                                    \
    s16x8 af[4], bq[4];                                                               \
    _Pragma("unroll")                                                                 \
    for (int i = 0; i < 4; ++i)                                                       \
      af[i] = *(const s16x8*)&AS[(wr * 64 + i * 16 + ln) * 64 + ((ks * 32 + hi * 8) ^ xo)]; \
    _Pragma("unroll")                                                                 \
    for (int j = 0; j < 4; ++j)                                                       \
      bq[j] = *(const s16x8*)&BS[(wc * 64 + j * 16 + ln) * 64 + ((ks * 32 + hi * 8) ^ xo)]; \
    _Pragma("unroll")                                                                 \
    for (int i = 0; i < 4; ++i)                                                       \
      _Pragma("unroll")                                                               \
      for (int j = 0; j < 4; ++j)                                                     \
        acc[i][j] = __builtin_amdgcn_mfma_f32_16x16x32_bf16(af[i], bq[j], acc[i][j], 0, 0, 0); \
  }

// ---------------- e1: hidden = gelu(gather(zb) @ W1[e] + b1) ---------------
__global__ __launch_bounds__(256, 2) void k_e1(const ushort_t* zb, const ushort_t* W1t,
                                               const float* b1, const int* ctrl,
                                               const int* pair_t, ushort_t* hidden) {
  __shared__ ushort_t As[2][8192];
  __shared__ ushort_t Bs[2][8192];
  __shared__ int pt[128];
  int sg = blockIdx.x >> 2, nt = blockIdx.x & 3;
  int e = ctrl[16 + sg];
  if (e < 0) return;
  int t = threadIdx.x;
  if (t < 128) pt[t] = pair_t[sg * 128 + t];
  __syncthreads();
  int n0 = nt * 128;
  const ushort_t* Bbase = W1t + (size_t)e * HH * RR;
  int lane = t & 63, wave = t >> 6;
  int wr = wave >> 1, wc = wave & 1;
  int ln = lane & 15, hi = lane >> 4;
  const int xo = (ln & 7) << 3;

  f32x4 acc[4][4];
  #pragma unroll
  for (int i = 0; i < 4; ++i)
    #pragma unroll
    for (int j = 0; j < 4; ++j) acc[i][j] = (f32x4){0.f, 0.f, 0.f, 0.f};

  #pragma unroll
  for (int u = 0; u < 4; ++u) {
    int idx = u * 256 + t;
    gll16(zb + (size_t)pt[idx >> 3] * RR + SWZ8(idx), &As[0][idx * 8]);
    gll16(Bbase + (size_t)(n0 + (idx >> 3)) * RR + SWZ8(idx), &Bs[0][idx * 8]);
  }
  __syncthreads();
  for (int s = 0; s < 4; ++s) {
    int cb = s & 1, xb = cb ^ 1;
    if (s < 3) {
      int k1 = (s + 1) * 64;
      #pragma unroll
      for (int u = 0; u < 4; ++u) {
        int idx = u * 256 + t;
        gll16(zb + (size_t)pt[idx >> 3] * RR + k1 + SWZ8(idx), &As[xb][idx * 8]);
        gll16(Bbase + (size_t)(n0 + (idx >> 3)) * RR + k1 + SWZ8(idx), &Bs[xb][idx * 8]);
      }
    }
    GEMM_COMPUTE(As[cb], Bs[cb]);
    __syncthreads();
  }
  #pragma unroll
  for (int i = 0; i < 4; ++i)
    #pragma unroll
    for (int j = 0; j < 4; ++j)
      #pragma unroll
      for (int r = 0; r < 4; ++r) {
        int pl = wr * 64 + i * 16 + hi * 4 + r;
        int col = n0 + wc * 64 + j * 16 + ln;
        float v = acc[i][j][r] + b1[e * HH + col];
        float g = 0.5f * v * (1.f + erff(v * 0.70710678118654752f));
        hidden[(size_t)(sg * 128 + pl) * HH + col] = f2bf(g);
      }
}

// ---------------- e2: eout[p] = w_p * (hidden @ W2[e] + b2)  (bf16 stores) --
__global__ __launch_bounds__(256, 2) void k_e2(const ushort_t* hidden, const ushort_t* W2t,
                                               const float* b2, const int* ctrl,
                                               const int* pair_t, const float* pair_w,
                                               ushort_t* eout) {
  __shared__ ushort_t As[2][8192];
  __shared__ ushort_t Bs[2][8192];
  __shared__ float pw[128];
  int sg = blockIdx.x >> 1, nt = blockIdx.x & 1;
  int e = ctrl[16 + sg];
  if (e < 0) return;
  int t = threadIdx.x;
  if (t < 128) pw[t] = pair_w[sg * 128 + t];
  __syncthreads();
  int n0 = nt * 128;
  const ushort_t* Abase = hidden + (size_t)sg * 128 * HH;
  const ushort_t* Bbase = W2t + (size_t)e * RR * HH;
  int lane = t & 63, wave = t >> 6;
  int wr = wave >> 1, wc = wave & 1;
  int ln = lane & 15, hi = lane >> 4;
  const int xo = (ln & 7) << 3;

  f32x4 acc[4][4];
  #pragma unroll
  for (int i = 0; i < 4; ++i)
    #pragma unroll
    for (int j = 0; j < 4; ++j) acc[i][j] = (f32x4){0.f, 0.f, 0.f, 0.f};

  #pragma unroll
  for (int u = 0; u < 4; ++u) {
    int idx = u * 256 + t;
    gll16(Abase + (size_t)(idx >> 3) * HH + SWZ8(idx), &As[0][idx * 8]);
    gll16(Bbase + (size_t)(n0 + (idx >> 3)) * HH + SWZ8(idx), &Bs[0][idx * 8]);
  }
  __syncthreads();
  for (int s = 0; s < 8; ++s) {
    int cb = s & 1, xb = cb ^ 1;
    if (s < 7) {
      int k1 = (s + 1) * 64;
      #pragma unroll
      for (int u = 0; u < 4; ++u) {
        int idx = u * 256 + t;
        gll16(Abase + (size_t)(idx >> 3) * HH + k1 + SWZ8(idx), &As[xb][idx * 8]);
        gll16(Bbase + (size_t)(n0 + (idx >> 3)) * HH + k1 + SWZ8(idx), &Bs[xb][idx * 8]);
      }
    }
    GEMM_COMPUTE(As[cb], Bs[cb]);
    __syncthreads();
  }
  #pragma unroll
  for (int i = 0; i < 4; ++i)
    #pragma unroll
    for (int j = 0; j < 4; ++j)
      #pragma unroll
      for (int r = 0; r < 4; ++r) {
        int pl = wr * 64 + i * 16 + hi * 4 + r;
        int col = n0 + wc * 64 + j * 16 + ln;
        float v = acc[i][j][r] + b2[e * RR + col];
        eout[(size_t)(sg * 128 + pl) * RR + col] = f2bf(pw[pl] * v);
      }
}

// ---------------- final: z_final = 0.75*z + 0.25*(eout0+eout1) -------------
__global__ __launch_bounds__(256) void k_final(const ushort_t* __restrict__ zb,
                                               const ushort_t* __restrict__ eout,
                                               const int* __restrict__ inv,
                                               const float* __restrict__ Uh,
                                               const float* __restrict__ bh,
                                               ushort_t* __restrict__ zb2,
                                               float* __restrict__ phalt) {
  __shared__ float luh[256];
  int t = threadIdx.x;
  if (t < 64) ((f32x4*)luh)[t] = ((const f32x4*)Uh)[t];
  __syncthreads();
  int tok = blockIdx.x * 64 + (t >> 2), q = t & 3;
  int i0 = inv[tok * 2], i1 = inv[tok * 2 + 1];
  const u16x8* z8 = (const u16x8*)(zb + (size_t)tok * RR + q * 64);
  const u16x8* ea = (const u16x8*)(eout + (size_t)i0 * RR + q * 64);
  const u16x8* eb = (const u16x8*)(eout + (size_t)i1 * RR + q * 64);
  ushort_t* o = zb2 + (size_t)tok * RR + q * 64;
  float acc = 0.f;
  #pragma unroll
  for (int it = 0; it < 8; ++it) {
    u16x8 zv = z8[it], av = ea[it], bv = eb[it];
    u16x8 pk;
    #pragma unroll
    for (int j = 0; j < 8; ++j) {
      float zf = 0.75f * bf2f(zv[j]) + 0.25f * (bf2f(av[j]) + bf2f(bv[j]));
      acc += zf * luh[q * 64 + it * 8 + j];
      pk[j] = f2bf(zf);
    }
    *(u16x8*)(o + it * 8) = pk;
  }
  acc += __shfl_xor(acc, 1, 64);
  acc += __shfl_xor(acc, 2, 64);
  if (q == 0) phalt[tok] = 1.f / (1.f + expf(-(acc + bh[0])));
}

// ---------------- gemm_u: h_new[T][D] = zb2 @ U ----------------------------
__global__ __launch_bounds__(256, 2) void k_gemm_u(const ushort_t* zb2, const ushort_t* Ut,
                                                   float* outp) {
  __shared__ ushort_t As[2][8192];
  __shared__ ushort_t Bs[2][8192];
  int hw = blockIdx.x;
  int bid = (hw & 7) * 256 + (hw >> 3);    // XCD swizzle (2048 = 8*256)
  int mt = bid >> 4, nt = bid & 15;
  int m0 = mt * 128, n0 = nt * 128;
  int t = threadIdx.x;
  int lane = t & 63, wave = t >> 6;
  int wr = wave >> 1, wc = wave & 1;
  int ln = lane & 15, hi = lane >> 4;
  const int xo = (ln & 7) << 3;

  f32x4 acc[4][4];
  #pragma unroll
  for (int i = 0; i < 4; ++i)
    #pragma unroll
    for (int j = 0; j < 4; ++j) acc[i][j] = (f32x4){0.f, 0.f, 0.f, 0.f};

  #pragma unroll
  for (int u = 0; u < 4; ++u) {
    int idx = u * 256 + t;
    gll16(zb2 + (size_t)(m0 + (idx >> 3)) * RR + SWZ8(idx), &As[0][idx * 8]);
    gll16(Ut + (size_t)(n0 + (idx >> 3)) * RR + SWZ8(idx), &Bs[0][idx * 8]);
  }
  __syncthreads();
  for (int s = 0; s < 4; ++s) {
    int cb = s & 1, xb = cb ^ 1;
    if (s < 3) {
      int k1 = (s + 1) * 64;
      #pragma unroll
      for (int u = 0; u < 4; ++u) {
        int idx = u * 256 + t;
        gll16(zb2 + (size_t)(m0 + (idx >> 3)) * RR + k1 + SWZ8(idx), &As[xb][idx * 8]);
        gll16(Ut + (size_t)(n0 + (idx >> 3)) * RR + k1 + SWZ8(idx), &Bs[xb][idx * 8]);
      }
    }
    GEMM_COMPUTE(As[cb], Bs[cb]);
    __syncthreads();
  }
  #pragma unroll
  for (int i = 0; i < 4; ++i)
    #pragma unroll
    for (int j = 0; j < 4; ++j)
      #pragma unroll
      for (int r = 0; r < 4; ++r) {
        int row = m0 + wr * 64 + i * 16 + hi * 4 + r;
        int col = n0 + wc * 64 + j * 16 + ln;
        outp[(size_t)row * DD + col] = acc[i][j][r];
      }
}

// ---------------------------------------------------------------------------
extern "C" void kernel_launch(void* const* d_in, const int* in_sizes, int n_in,
                              void* d_out, int out_size, void* d_ws, size_t ws_size,
                              hipStream_t stream) {
  (void)in_sizes; (void)n_in; (void)out_size;
  const float* h  = (const float*)d_in[0];
  const float* V  = (const float*)d_in[1];
  const float* U  = (const float*)d_in[2];
  const float* Wr = (const float*)d_in[3];
  const float* br = (const float*)d_in[4];
  const float* W1 = (const float*)d_in[5];
  const float* b1 = (const float*)d_in[6];
  const float* W2 = (const float*)d_in[7];
  const float* b2 = (const float*)d_in[8];
  const float* Wh = (const float*)d_in[9];
  const float* bh = (const float*)d_in[10];
  float* outp = (float*)d_out;
  char* w = (char*)d_ws;

  constexpr size_t OFF_VT    = 0;          // 1 MB   Vt   [256][2048] bf16
  constexpr size_t OFF_UT    = 1048576;    // 1 MB   Ut   [2048][256] bf16
  constexpr size_t OFF_W1T   = 2097152;    // 2 MB   W1t  [8][512][256] bf16
  constexpr size_t OFF_W2T   = 4194304;    // 2 MB   W2t  [8][256][512] bf16
  constexpr size_t OFF_VEFFT = 6291456;    // 64 KB  VeffT [8][2048] f32
  constexpr size_t OFF_UHV   = 6356992;    // 4 KB   Uh [256] f32
  constexpr size_t OFF_TOPI  = 6361088;    // 128 KB
  constexpr size_t OFF_TOPW  = 6492160;    // 128 KB
  constexpr size_t OFF_INV   = 6623232;    // 128 KB
  constexpr size_t OFF_CTRL  = 6754304;    // 4 KB   (zeroed by k_prep)
  constexpr size_t OFF_PT    = 6758400;    // 132 KB (zeroed by k_prep)
  constexpr size_t OFF_PW    = 6893568;    // 132 KB (zeroed by k_prep)
  constexpr size_t OFF_ZB    = 7028736;    // 8 MB   zb [16384][256] bf16
  constexpr size_t OFF_EOUT  = 15417344;   // 16.5MB eout [33792][256] bf16
  constexpr size_t OFF_HID   = 32718848;   // 33 MB  hidden [33792][512] bf16
  constexpr size_t OFF_ZB2   = OFF_HID;    // aliases hidden (dead after e2)
  constexpr size_t WS_NEED   = 67321856;
  if (ws_size < WS_NEED) return;

  ushort_t* Vt    = (ushort_t*)(w + OFF_VT);
  ushort_t* Ut    = (ushort_t*)(w + OFF_UT);
  ushort_t* W1t   = (ushort_t*)(w + OFF_W1T);
  ushort_t* W2t   = (ushort_t*)(w + OFF_W2T);
  float*    VeffT = (float*)(w + OFF_VEFFT);
  float*    Uh    = (float*)(w + OFF_UHV);
  int*      topi  = (int*)(w + OFF_TOPI);
  float*    topw  = (float*)(w + OFF_TOPW);
  int*      inv   = (int*)(w + OFF_INV);
  int*      ctrl  = (int*)(w + OFF_CTRL);
  int*      pair_t= (int*)(w + OFF_PT);
  float*    pair_w= (float*)(w + OFF_PW);
  ushort_t* zb    = (ushort_t*)(w + OFF_ZB);
  ushort_t* eout  = (ushort_t*)(w + OFF_EOUT);
  ushort_t* hidden= (ushort_t*)(w + OFF_HID);
  ushort_t* zb2   = (ushort_t*)(w + OFF_ZB2);

  // k_prep also zeroes [OFF_CTRL, OFF_ZB) — 17152 dword4s (ctrl + pair lists)
  k_prep<<<3211, 256, 0, stream>>>(V, U, W1, W2, Wr, Wh, Vt, Ut, W1t, W2t,
                                   VeffT, Uh, (u32x4*)(w + OFF_CTRL));
  k_front<<<512, 256, 0, stream>>>(h, Vt, VeffT, br, zb, topi, topw, ctrl);
  k_bases<<<1, 256, 0, stream>>>(ctrl);
  k_scatter<<<128, 256, 0, stream>>>(topi, topw, ctrl, pair_t, pair_w, inv);
  k_e1<<<NSEG_MAX * 4, 256, 0, stream>>>(zb, W1t, b1, ctrl, pair_t, hidden);
  k_e2<<<NSEG_MAX * 2, 256, 0, stream>>>(hidden, W2t, b2, ctrl, pair_t, pair_w, eout);
  k_final<<<256, 256, 0, stream>>>(zb, eout, inv, Uh, bh, zb2, outp + (size_t)TK * DD);
  k_gemm_u<<<2048, 256, 0, stream>>>(zb2, Ut, outp);
}